// Round 8
// baseline (616.803 us; speedup 1.0000x reference)
//
#include <hip/hip_runtime.h>

typedef unsigned int u32;
typedef unsigned short u16;

#define N_NODES 50000
#define N_EDGES 400000
#define IN_F 512
#define HID 512
#define OUT_F 256
#define N_CELL 1000
#define N_DIM 128
#define N_SEL 8192
#define N_C 1024
#define MPAD 50176  // 392*128 = 196*256, node count padded to GEMM tiles

#define SCAN_B 256
#define SCAN_NB ((N_NODES + SCAN_B - 1) / SCAN_B)  // 196

typedef __bf16 bf16x8 __attribute__((ext_vector_type(8)));
typedef float f32x4 __attribute__((ext_vector_type(4)));

__device__ __forceinline__ u16 f2bf(float f) {
    u32 u = __builtin_bit_cast(u32, f);
    u32 r = (u + 0x7fffu + ((u >> 16) & 1u)) >> 16;  // RNE
    return (u16)r;
}
__device__ __forceinline__ float bf2f(u32 bits16) {
    return __builtin_bit_cast(float, bits16 << 16);
}

// async 16B global -> LDS (dest = wave-uniform base + lane*16)
__device__ __forceinline__ void async_copy16(const u16* g, u16* l) {
    __builtin_amdgcn_global_load_lds(
        (const __attribute__((address_space(1))) void*)g,
        (__attribute__((address_space(3))) void*)l, 16, 0, 0);
}

// ---------------- graph prep ----------------

__global__ void degrees_kernel(const int* __restrict__ src, const int* __restrict__ dst,
                               int* __restrict__ degO, int* __restrict__ degI) {
    int e = blockIdx.x * 256 + threadIdx.x;
    if (e < N_EDGES) {
        atomicAdd(&degO[src[e]], 1);
        atomicAdd(&degI[dst[e]], 1);
    }
}

// --- 3-phase parallel exclusive scan of degI -> offs[0..N_NODES] ---
__global__ void scan_blocksum_kernel(const int* __restrict__ deg, int* __restrict__ bsum) {
    __shared__ int sh[SCAN_B];
    int i = blockIdx.x * SCAN_B + threadIdx.x;
    int v = (i < N_NODES) ? deg[i] : 0;
    sh[threadIdx.x] = v;
    __syncthreads();
    for (int off = SCAN_B / 2; off > 0; off >>= 1) {
        if (threadIdx.x < off) sh[threadIdx.x] += sh[threadIdx.x + off];
        __syncthreads();
    }
    if (threadIdx.x == 0) bsum[blockIdx.x] = sh[0];
}

__global__ void scan_bsum_kernel(const int* __restrict__ bsum, int* __restrict__ boff) {
    __shared__ int sh[SCAN_B];
    const int t = threadIdx.x;
    int v = (t < SCAN_NB) ? bsum[t] : 0;
    sh[t] = v;
    __syncthreads();
    for (int off = 1; off < SCAN_B; off <<= 1) {
        int u = (t >= off) ? sh[t - off] : 0;
        __syncthreads();
        sh[t] += u;
        __syncthreads();
    }
    if (t < SCAN_NB) boff[t] = sh[t] - v;  // exclusive
}

__global__ void scan_final_kernel(const int* __restrict__ deg, const int* __restrict__ boff,
                                  int* __restrict__ offs) {
    __shared__ int sh[SCAN_B];
    const int t = threadIdx.x;
    int i = blockIdx.x * SCAN_B + t;
    int v = (i < N_NODES) ? deg[i] : 0;
    sh[t] = v;
    __syncthreads();
    for (int off = 1; off < SCAN_B; off <<= 1) {
        int u = (t >= off) ? sh[t - off] : 0;
        __syncthreads();
        sh[t] += u;
        __syncthreads();
    }
    if (i < N_NODES) offs[i] = boff[blockIdx.x] + sh[t] - v;
    if (i == 0) offs[N_NODES] = N_EDGES;  // total degree = edge count
}

__global__ void fill_csr_kernel(const int* __restrict__ src, const int* __restrict__ dst,
                                int* __restrict__ cursor, const int* __restrict__ offs,
                                int* __restrict__ csr) {
    int e = blockIdx.x * 256 + threadIdx.x;
    if (e < N_EDGES) {
        int d = dst[e];
        int slot = atomicAdd(&cursor[d], 1);
        csr[offs[d] + slot] = src[e];
    }
}

__global__ void norms_kernel(const int* __restrict__ degO, const int* __restrict__ degI,
                             float* __restrict__ ns, float* __restrict__ nd) {
    int i = blockIdx.x * 256 + threadIdx.x;
    if (i < N_NODES) {
        ns[i] = degO[i] > 0 ? rsqrtf((float)degO[i]) : 0.f;
        nd[i] = degI[i] > 0 ? rsqrtf((float)degI[i]) : 0.f;
    }
}

// ---------------- conversions ----------------

// src[K][N] fp32 -> dst[N][K] bf16 (weights, small)
__global__ void trans_bf16_kernel(const float* __restrict__ src, u16* __restrict__ dst,
                                  int K, int N) {
    int i = blockIdx.x * 256 + threadIdx.x;
    if (i >= K * N) return;
    int n = i / K, k = i % K;
    dst[i] = f2bf(src[k * N + n]);
}

// x fp32 [N_NODES][512] -> bf16 [MPAD][512], zero pad rows
__global__ void convert_x_kernel(const float* __restrict__ x, u16* __restrict__ xb) {
    int i = blockIdx.x * 256 + threadIdx.x;  // one per 4 elems; grid exact
    int base = i * 4;
    int m = base >> 9;
    ushort4 o;
    if (m < N_NODES) {
        float4 v = *(const float4*)(x + base);
        o.x = f2bf(v.x); o.y = f2bf(v.y); o.z = f2bf(v.z); o.w = f2bf(v.w);
    } else {
        o = make_ushort4(0, 0, 0, 0);
    }
    *(ushort4*)(xb + base) = o;
}

// eb[c][:] = bf16(emb[c_indices[c]][:])
__global__ void gather_emb_kernel(const float* __restrict__ emb, const int* __restrict__ cidx,
                                  u16* __restrict__ eb) {
    int c = blockIdx.x, f = threadIdx.x;
    eb[c * N_DIM + f] = f2bf(emb[(size_t)cidx[c] * N_DIM + f]);
}

// ---------------- 256x256 MFMA GEMM for the two big layers ----------------
// C[M][N] = A[M][K] @ B[N][K]^T, bf16 out with row scale.  512 thr / 8 waves
// (2M x 4N), wave tile 128x64 (8x4 of 16x16x32), grid (M/256, N/256).
//
// WHY: staged-traffic arithmetic.  At 128^2 tiles the load path moves
// A*(N/128) + B*(M/128) = 404 MB per big GEMM ~= 64 us at 6.3 TB/s — the
// measured 71 us plateau.  256^2 halves it to 202 MB.  Schedule pieces are
// all previously verified: region staging + chunk-XOR swizzle (v2/v6),
// 3-buffer depth-2 counted vmcnt(4) (v7, correctness-proven on HW) — needed
// here because at 1 block/CU there is no second block to hide a drain.
__global__ __launch_bounds__(512, 2) void gemm256(
    const u16* __restrict__ A, const u16* __restrict__ B,
    u16* __restrict__ C, const float* __restrict__ scale, int nScale,
    int N, int K) {
    __shared__ __align__(16) u16 As[3 * 8192];  // 3 buffers x 256x32
    __shared__ __align__(16) u16 Bs[3 * 8192];
    const int t = threadIdx.x;
    const int m0 = blockIdx.x * 256, n0 = blockIdx.y * 256;
    const int l = t & 63, w = t >> 6;
    const int lr = l & 15, quad = l >> 4;
    const int wm = (w >> 2) << 7;   // 0 / 128
    const int wn = (w & 3) << 6;    // 0 / 64 / 128 / 192

    // staging: 16 regions of 16 rows per matrix; wave w does regions w, w+8.
    // lane covers row = r*16 + l/4; global chunk pre-swizzled so LDS slot
    // (row, c) holds chunk c ^ ((row>>1)&3).
    const int lrow = l >> 2;
    const int kof = (((l & 3) ^ ((l >> 3) & 3)) << 3);
    const int r0 = w, r1 = w + 8;
    const u16* gA0 = A + (size_t)(m0 + r0 * 16 + lrow) * K + kof;
    const u16* gA1 = A + (size_t)(m0 + r1 * 16 + lrow) * K + kof;
    const u16* gB0 = B + (size_t)(n0 + r0 * 16 + lrow) * K + kof;
    const u16* gB1 = B + (size_t)(n0 + r1 * 16 + lrow) * K + kof;
    u16* lA0 = As + r0 * 512;  // wave-uniform LDS bases (buf b = +b*8192)
    u16* lA1 = As + r1 * 512;
    u16* lB0 = Bs + r0 * 512;
    u16* lB1 = Bs + r1 * 512;

    f32x4 acc[8][4] = {};

    const int niter = K >> 5;
    auto stage = [&](int j, int bo) {
        const int ks = j << 5;
        async_copy16(gA0 + ks, lA0 + bo);
        async_copy16(gA1 + ks, lA1 + bo);
        async_copy16(gB0 + ks, lB0 + bo);
        async_copy16(gB1 + ks, lB1 + bo);
    };

    // prologue: fill pipeline 2 deep
    stage(0, 0);
    if (niter > 1) stage(1, 8192);

    // read swizzle: chunk quad of row stored at chunk quad ^ ((l>>1)&3)
    const int qoff = ((quad ^ ((l >> 1) & 3)) << 3);

    int cur = 0;       // elem offset of buf[it%3]
    int nx2 = 16384;   // elem offset of buf[(it+2)%3]
    for (int it = 0; it < niter; ++it) {
        // retire this iter's 4 DMAs; keep next tile's 4 in flight
        if (it + 1 < niter) asm volatile("s_waitcnt vmcnt(4)" ::: "memory");
        else                asm volatile("s_waitcnt vmcnt(0)" ::: "memory");
        __builtin_amdgcn_s_barrier();
        __builtin_amdgcn_sched_barrier(0);  // nothing crosses the barrier
        if (it + 2 < niter) stage(it + 2, nx2);
        bf16x8 af[8], bg[4];
#pragma unroll
        for (int i = 0; i < 8; ++i)
            af[i] = *(const bf16x8*)&As[cur + (wm + i * 16 + lr) * 32 + qoff];
#pragma unroll
        for (int j = 0; j < 4; ++j)
            bg[j] = *(const bf16x8*)&Bs[cur + (wn + j * 16 + lr) * 32 + qoff];
#pragma unroll
        for (int i = 0; i < 8; ++i)
#pragma unroll
            for (int j = 0; j < 4; ++j)
                acc[i][j] = __builtin_amdgcn_mfma_f32_16x16x32_bf16(af[i], bg[j], acc[i][j], 0, 0, 0);
        cur = (cur == 16384) ? 0 : cur + 8192;
        nx2 = (nx2 == 16384) ? 0 : nx2 + 8192;
    }

    // C/D layout (m89-verified): col = lane&15, row = quad*4 + reg
#pragma unroll
    for (int i = 0; i < 8; ++i) {
        int rbase = m0 + wm + i * 16 + quad * 4;
#pragma unroll
        for (int j = 0; j < 4; ++j) {
            int col = n0 + wn + j * 16 + lr;
#pragma unroll
            for (int r = 0; r < 4; ++r) {
                int rg = rbase + r;
                float sc = rg < nScale ? scale[rg] : 0.f;
                C[(size_t)rg * N + col] = f2bf(acc[i][j][r] * sc);
            }
        }
    }
}

// ---------------- generic MFMA GEMM (v0 schedule, small GEMMs) ----------------
// C = A @ B^T ; optional A-row gather (aidx), row scale, col bias, relu;
// bf16 or f32 out.  128x128 tile, 256 threads / 4 waves, wave tile 64x64.
// v0 schedule (best-measured config): 2 LDS buffers, one __syncthreads per
// K-iter.  Chunk-XOR swizzle (verified correct, conflict-free).
__global__ __launch_bounds__(256, 4) void gemm_bf16_nt(
    const u16* __restrict__ A, const u16* __restrict__ B,
    const int* __restrict__ aidx,
    u16* __restrict__ Cb, float* __restrict__ Cf,
    const float* __restrict__ scale, int nScale,
    const float* __restrict__ bias, int doRelu,
    int N, int K) {
    __shared__ __align__(16) u16 As[2 * 4096];  // 2 buffers x 128x32
    __shared__ __align__(16) u16 Bs[2 * 4096];
    const int t = threadIdx.x;
    const int m0 = blockIdx.x * 128, n0 = blockIdx.y * 128;
    const int l = t & 63, w = t >> 6;
    const int wm = (w >> 1) << 6, wn = (w & 1) << 6;
    const int lr = l & 15, quad = l >> 4;

    const int lrow = l >> 2;
    const int kof = (((l & 3) ^ ((l >> 3) & 3)) << 3);
    const int r0 = w, r1 = w + 4;
    int ar0 = m0 + r0 * 16 + lrow;
    int ar1 = m0 + r1 * 16 + lrow;
    if (aidx) { ar0 = aidx[ar0]; ar1 = aidx[ar1]; }
    const u16* gA0 = A + (size_t)ar0 * K + kof;
    const u16* gA1 = A + (size_t)ar1 * K + kof;
    const u16* gB0 = B + (size_t)(n0 + r0 * 16 + lrow) * K + kof;
    const u16* gB1 = B + (size_t)(n0 + r1 * 16 + lrow) * K + kof;
    u16* lA0 = As + r0 * 512;  // wave-uniform LDS bases (buf0; buf1 = +4096)
    u16* lA1 = As + r1 * 512;
    u16* lB0 = Bs + r0 * 512;
    u16* lB1 = Bs + r1 * 512;

    f32x4 acc[4][4] = {};

    // prologue: stage iter 0 into buf0
    async_copy16(gA0, lA0);
    async_copy16(gA1, lA1);
    async_copy16(gB0, lB0);
    async_copy16(gB1, lB1);

    const int qoff = ((quad ^ ((l >> 1) & 3)) << 3);

    const int niter = K >> 5;
    for (int it = 0; it < niter; ++it) {
        const int cur = (it & 1) << 12;   // 0 / 4096
        const int nxt = 4096 - cur;
        __syncthreads();  // drains DMA into buf[cur]; prior reads of buf[nxt] done
        if (it + 1 < niter) {
            const int ks = (it + 1) << 5;
            async_copy16(gA0 + ks, lA0 + nxt);
            async_copy16(gA1 + ks, lA1 + nxt);
            async_copy16(gB0 + ks, lB0 + nxt);
            async_copy16(gB1 + ks, lB1 + nxt);
        }
        bf16x8 af[4], bg[4];
#pragma unroll
        for (int i = 0; i < 4; ++i)
            af[i] = *(const bf16x8*)&As[cur + (wm + i * 16 + lr) * 32 + qoff];
#pragma unroll
        for (int j = 0; j < 4; ++j)
            bg[j] = *(const bf16x8*)&Bs[cur + (wn + j * 16 + lr) * 32 + qoff];
#pragma unroll
        for (int i = 0; i < 4; ++i)
#pragma unroll
            for (int j = 0; j < 4; ++j)
                acc[i][j] = __builtin_amdgcn_mfma_f32_16x16x32_bf16(af[i], bg[j], acc[i][j], 0, 0, 0);
    }

    // C/D layout (m89-verified): col = lane&15, row = quad*4 + reg
#pragma unroll
    for (int i = 0; i < 4; ++i) {
        int rbase = m0 + wm + i * 16 + quad * 4;
#pragma unroll
        for (int j = 0; j < 4; ++j) {
            int col = n0 + wn + j * 16 + lr;
            float bv = bias ? bias[col] : 0.f;
#pragma unroll
            for (int r = 0; r < 4; ++r) {
                int rg = rbase + r;
                float sc = scale ? (rg < nScale ? scale[rg] : 0.f) : 1.f;
                float v = acc[i][j][r] * sc + bv;
                if (doRelu) v = fmaxf(v, 0.f);
                if (Cb) Cb[(size_t)rg * N + col] = f2bf(v);
                else    Cf[(size_t)rg * N + col] = v;
            }
        }
    }
}

// ---------------- CSR aggregation: H[n] = nsOut[n]? * relu(nd[n]*sum T[s] + b) -------------
template <int W32>  // u32 words per lane: 4 (F=512) or 2 (F=256)
struct AggVec;
template <> struct AggVec<4> { using T = uint4; };
template <> struct AggVec<2> { using T = uint2; };

template <int F>
__global__ __launch_bounds__(256) void aggregate_kernel(
    const u16* __restrict__ T, const int* __restrict__ csr,
    const int* __restrict__ offs, const float* __restrict__ nd,
    const float* __restrict__ bias, const float* __restrict__ nsOut,
    u16* __restrict__ H) {
    constexpr int W32 = F / 128;  // u32 words per lane
    using VT = typename AggVec<W32>::T;
    const int t = threadIdx.x, w = t >> 6, l = t & 63;
    const int node = blockIdx.x * 4 + w;
    u32* __restrict__ Hrow = (u32*)H + (size_t)node * (F / 2) + l * W32;
    if (node >= N_NODES) {
        VT z = {};
        *(VT*)Hrow = z;
        return;
    }
    const int s0 = __builtin_amdgcn_readfirstlane(offs[node]);
    const int s1 = __builtin_amdgcn_readfirstlane(offs[node + 1]);
    const u32* __restrict__ Tb = (const u32*)T + l * W32;

    float acc[4][2 * W32];
#pragma unroll
    for (int c = 0; c < 4; ++c)
#pragma unroll
        for (int j = 0; j < 2 * W32; ++j) acc[c][j] = 0.f;

    int e = s0;
    for (; e + 8 <= s1; e += 8) {  // 8 loads in flight, 4 accumulator chains
        int si[8];
#pragma unroll
        for (int c = 0; c < 8; ++c) si[c] = csr[e + c];
        VT v[8];
#pragma unroll
        for (int c = 0; c < 8; ++c)
            v[c] = *(const VT*)(Tb + (size_t)si[c] * (F / 2));
#pragma unroll
        for (int c = 0; c < 8; ++c) {
            const u32* vv = (const u32*)&v[c];
#pragma unroll
            for (int j = 0; j < W32; ++j) {
                acc[c & 3][2 * j] += bf2f(vv[j] & 0xffffu);
                acc[c & 3][2 * j + 1] += bf2f(vv[j] >> 16);
            }
        }
    }
    for (; e + 4 <= s1; e += 4) {
        int si[4];
#pragma unroll
        for (int c = 0; c < 4; ++c) si[c] = csr[e + c];
        VT v[4];
#pragma unroll
        for (int c = 0; c < 4; ++c)
            v[c] = *(const VT*)(Tb + (size_t)si[c] * (F / 2));
#pragma unroll
        for (int c = 0; c < 4; ++c) {
            const u32* vv = (const u32*)&v[c];
#pragma unroll
            for (int j = 0; j < W32; ++j) {
                acc[c][2 * j] += bf2f(vv[j] & 0xffffu);
                acc[c][2 * j + 1] += bf2f(vv[j] >> 16);
            }
        }
    }
    for (; e < s1; ++e) {
        int s = csr[e];
        VT v = *(const VT*)(Tb + (size_t)s * (F / 2));
        const u32* vv = (const u32*)&v;
#pragma unroll
        for (int j = 0; j < W32; ++j) {
            acc[0][2 * j] += bf2f(vv[j] & 0xffffu);
            acc[0][2 * j + 1] += bf2f(vv[j] >> 16);
        }
    }

    const float ndv = nd[node];
    const float nsv = nsOut ? nsOut[node] : 1.f;
    u32 ow[W32];
#pragma unroll
    for (int j = 0; j < W32; ++j) {
        float a0 = acc[0][2 * j] + acc[1][2 * j] + acc[2][2 * j] + acc[3][2 * j];
        float a1 = acc[0][2 * j + 1] + acc[1][2 * j + 1] + acc[2][2 * j + 1] + acc[3][2 * j + 1];
        float r0 = fmaxf(fmaf(a0, ndv, bias[l * 2 * W32 + 2 * j]), 0.f) * nsv;
        float r1 = fmaxf(fmaf(a1, ndv, bias[l * 2 * W32 + 2 * j + 1]), 0.f) * nsv;
        ow[j] = (u32)f2bf(r0) | ((u32)f2bf(r1) << 16);
    }
    VT o;
    u32* op = (u32*)&o;
#pragma unroll
    for (int j = 0; j < W32; ++j) op[j] = ow[j];
    *(VT*)Hrow = o;
}

// ---------------- selected-destination aggregation (layer 3, F=512) ----------------
// S[slot] = nd[xidx[slot]] * sum_{src in N(xidx[slot])} Tn[src]
__global__ __launch_bounds__(256) void aggregate_sel_kernel(
    const u16* __restrict__ Tn, const int* __restrict__ csr,
    const int* __restrict__ offs, const float* __restrict__ nd,
    const int* __restrict__ xidx, u16* __restrict__ S) {
    const int t = threadIdx.x, w = t >> 6, l = t & 63;
    const int slot = blockIdx.x * 4 + w;
    const int node = __builtin_amdgcn_readfirstlane(xidx[slot]);
    const int s0 = __builtin_amdgcn_readfirstlane(offs[node]);
    const int s1 = __builtin_amdgcn_readfirstlane(offs[node + 1]);
    const u32* __restrict__ Tb = (const u32*)Tn + l * 4;
    u32* __restrict__ Srow = (u32*)S + (size_t)slot * 256 + l * 4;

    float acc[4][8];
#pragma unroll
    for (int c = 0; c < 4; ++c)
#pragma unroll
        for (int j = 0; j < 8; ++j) acc[c][j] = 0.f;

    int e = s0;
    for (; e + 8 <= s1; e += 8) {
        int si[8];
#pragma unroll
        for (int c = 0; c < 8; ++c) si[c] = csr[e + c];
        uint4 v[8];
#pragma unroll
        for (int c = 0; c < 8; ++c)
            v[c] = *(const uint4*)(Tb + (size_t)si[c] * 256);
#pragma unroll
        for (int c = 0; c < 8; ++c) {
            const u32* vv = (const u32*)&v[c];
#pragma unroll
            for (int j = 0; j < 4; ++j) {
                acc[c & 3][2 * j] += bf2f(vv[j] & 0xffffu);
                acc[c & 3][2 * j + 1] += bf2f(vv[j] >> 16);
            }
        }
    }
    for (; e + 4 <= s1; e += 4) {
        int si[4];
#pragma unroll
        for (int c = 0; c < 4; ++c) si[c] = csr[e + c];
        uint4 v[4];
#pragma unroll
        for (int c = 0; c < 4; ++c)
            v[c] = *(const uint4*)(Tb + (size_t)si[c] * 256);
#pragma unroll
        for (int c = 0; c < 4; ++c) {
            const u32* vv = (const u32*)&v[c];
#pragma unroll
            for (int j = 0; j < 4; ++j) {
                acc[c][2 * j] += bf2f(vv[j] & 0xffffu);
                acc[c][2 * j + 1] += bf2f(vv[j] >> 16);
            }
        }
    }
    for (; e < s1; ++e) {
        int s = csr[e];
        uint4 v = *(const uint4*)(Tb + (size_t)s * 256);
        const u32* vv = (const u32*)&v;
#pragma unroll
        for (int j = 0; j < 4; ++j) {
            acc[0][2 * j] += bf2f(vv[j] & 0xffffu);
            acc[0][2 * j + 1] += bf2f(vv[j] >> 16);
        }
    }

    const float ndv = nd[node];
    uint4 o;
    u32* op = (u32*)&o;
#pragma unroll
    for (int j = 0; j < 4; ++j) {
        float a0 = (acc[0][2 * j] + acc[1][2 * j] + acc[2][2 * j] + acc[3][2 * j]) * ndv;
        float a1 = (acc[0][2 * j + 1] + acc[1][2 * j + 1] + acc[2][2 * j + 1] + acc[3][2 * j + 1]) * ndv;
        op[j] = (u32)f2bf(a0) | ((u32)f2bf(a1) << 16);
    }
    *(uint4*)Srow = o;
}

// ---------------- launch ----------------

extern "C" void kernel_launch(void* const* d_in, const int* in_sizes, int n_in,
                              void* d_out, int out_size, void* d_ws, size_t ws_size,
                              hipStream_t stream) {
    const float* x   = (const float*)d_in[0];
    const int*   src = (const int*)d_in[1];
    const int*   dst = (const int*)d_in[2];
    const int*   xidx= (const int*)d_in[3];
    const int*   cidx= (const int*)d_in[4];
    const float* W1  = (const float*)d_in[5];
    const float* b1  = (const float*)d_in[6];
    const float* W2  = (const float*)d_in[7];
    const float* b2  = (const float*)d_in[8];
    const float* W3  = (const float*)d_in[9];
    const float* b3  = (const float*)d_in[10];
    const float* Wp  = (const float*)d_in[11];
    const float* bp  = (const float*)d_in[12];
    const float* emb = (const float*)d_in[13];
    float* out = (float*)d_out;

    char* p = (char*)d_ws;
    auto alloc = [&](size_t bytes) {
        char* r = p;
        p += (bytes + 255) & ~(size_t)255;
        return r;
    };
    u16* T    = (u16*)alloc((size_t)MPAD * 512 * 2);   // transformed features (bf16, ns-scaled)
    u16* HX   = (u16*)alloc((size_t)MPAD * 512 * 2);   // x_bf16 / h1 / h2' (in-place rotate)
    u16* W1T  = (u16*)alloc((size_t)512 * 512 * 2);
    u16* W2T  = (u16*)alloc((size_t)512 * 512 * 2);
    u16* W3T  = (u16*)alloc((size_t)256 * 512 * 2);
    u16* WpT  = (u16*)alloc((size_t)128 * 256 * 2);
    u16* Ssel = (u16*)alloc((size_t)N_SEL * 512 * 2);  // selected aggregate (layer 3 input)
    u16* encb = (u16*)alloc((size_t)N_SEL * OUT_F * 2);
    u16* projb= (u16*)alloc((size_t)N_SEL * N_DIM * 2);
    u16* eb   = (u16*)alloc((size_t)N_C * N_DIM * 2);
    int* degO   = (int*)alloc(N_NODES * 4);
    int* degI   = (int*)alloc(N_NODES * 4);
    int* cursor = (int*)alloc(N_NODES * 4);
    int* offs   = (int*)alloc((N_NODES + 1) * 4);
    float* ns   = (float*)alloc(N_NODES * 4);
    float* nd   = (float*)alloc(N_NODES * 4);
    int* csr    = (int*)alloc(N_EDGES * 4);
    int* bsum   = (int*)alloc(SCAN_NB * 4);
    int* boff   = (int*)alloc(SCAN_NB * 4);
    if ((size_t)(p - (char*)d_ws) > ws_size) return;  // scratch too small — bail

    // graph prep
    hipMemsetAsync(degO, 0, (size_t)((char*)offs - (char*)degO), stream);  // degO,degI,cursor
    degrees_kernel<<<(N_EDGES + 255) / 256, 256, 0, stream>>>(src, dst, degO, degI);
    scan_blocksum_kernel<<<SCAN_NB, SCAN_B, 0, stream>>>(degI, bsum);
    scan_bsum_kernel<<<1, SCAN_B, 0, stream>>>(bsum, boff);
    scan_final_kernel<<<SCAN_NB, SCAN_B, 0, stream>>>(degI, boff, offs);
    fill_csr_kernel<<<(N_EDGES + 255) / 256, 256, 0, stream>>>(src, dst, cursor, offs, csr);
    norms_kernel<<<(N_NODES + 255) / 256, 256, 0, stream>>>(degO, degI, ns, nd);

    // weight transposes + input conversion
    trans_bf16_kernel<<<(512 * 512) / 256, 256, 0, stream>>>(W1, W1T, 512, 512);
    trans_bf16_kernel<<<(512 * 512) / 256, 256, 0, stream>>>(W2, W2T, 512, 512);
    trans_bf16_kernel<<<(512 * 256) / 256, 256, 0, stream>>>(W3, W3T, 512, 256);
    trans_bf16_kernel<<<(256 * 128) / 256, 256, 0, stream>>>(Wp, WpT, 256, 128);
    convert_x_kernel<<<(MPAD * 512 / 4) / 256, 256, 0, stream>>>(x, HX);
    gather_emb_kernel<<<N_C, N_DIM, 0, stream>>>(emb, cidx, eb);

    // layer 1: T = (ns.x) @ W1 ; h1 = relu(nd * agg(T) + b1)
    gemm256<<<dim3(MPAD / 256, 512 / 256), 512, 0, stream>>>(
        HX, W1T, T, ns, N_NODES, 512, 512);
    aggregate_kernel<512><<<MPAD / 4, 256, 0, stream>>>(T, csr, offs, nd, b1, nullptr, HX);
    // layer 2: T = (ns.h1) @ W2 ; h2' = ns * relu(nd * agg(T) + b2)   (ns pre-applied for layer 3)
    gemm256<<<dim3(MPAD / 256, 512 / 256), 512, 0, stream>>>(
        HX, W2T, T, ns, N_NODES, 512, 512);
    aggregate_kernel<512><<<MPAD / 4, 256, 0, stream>>>(T, csr, offs, nd, b2, ns, HX);
    // layer 3 AGGREGATE-FIRST at the 8192 selected destinations only:
    // Ssel[s] = nd[xidx[s]] * sum h2'[src] ; enc = relu(Ssel @ W3 + b3)
    aggregate_sel_kernel<<<N_SEL / 4, 256, 0, stream>>>(HX, csr, offs, nd, xidx, Ssel);
    gemm_bf16_nt<<<dim3(N_SEL / 128, 256 / 128), 256, 0, stream>>>(
        Ssel, W3T, nullptr, encb, nullptr, nullptr, 0, b3, 1, 256, 512);

    // proj = enc @ Wp + bp   (enc already in x_indices order — no gather)
    gemm_bf16_nt<<<dim3(N_SEL / 128, 1), 256, 0, stream>>>(
        encb, WpT, nullptr, projb, nullptr, nullptr, 0, bp, 0, N_DIM, 256);
    // out = e @ proj^T   (fp32 output)
    gemm_bf16_nt<<<dim3(N_C / 128, N_SEL / 128), 256, 0, stream>>>(
        eb, projb, nullptr, nullptr, out, nullptr, 0, nullptr, 0, N_SEL, N_DIM);
}

// Round 10
// 554.558 us; speedup vs baseline: 1.1122x; 1.1122x over previous
//
#include <hip/hip_runtime.h>

typedef unsigned int u32;
typedef unsigned short u16;

#define N_NODES 50000
#define N_EDGES 400000
#define IN_F 512
#define HID 512
#define OUT_F 256
#define N_CELL 1000
#define N_DIM 128
#define N_SEL 8192
#define N_C 1024
#define MPAD 50176  // 392*128, node count padded to 128-row GEMM tiles

#define SCAN_B 256
#define SCAN_NB ((N_NODES + SCAN_B - 1) / SCAN_B)  // 196

// prep_fused block ranges
#define NB_CVT 25088   // convert_x: MPAD*512/4/256
#define NB_DEG 1563    // degrees: ceil(N_EDGES/256)
#define NB_W12 1024    // trans 512x512
#define NB_W3  512     // trans 512x256
#define NB_WP  128     // trans 256x128
#define NB_EMB 512     // gather_emb: N_C*N_DIM/256 = 1024*128/256  (r9 bug: was 500 = N_CELL-based)

typedef __bf16 bf16x8 __attribute__((ext_vector_type(8)));
typedef float f32x4 __attribute__((ext_vector_type(4)));

__device__ __forceinline__ u16 f2bf(float f) {
    u32 u = __builtin_bit_cast(u32, f);
    u32 r = (u + 0x7fffu + ((u >> 16) & 1u)) >> 16;  // RNE
    return (u16)r;
}
__device__ __forceinline__ float bf2f(u32 bits16) {
    return __builtin_bit_cast(float, bits16 << 16);
}

// async 16B global -> LDS (dest = wave-uniform base + lane*16)
__device__ __forceinline__ void async_copy16(const u16* g, u16* l) {
    __builtin_amdgcn_global_load_lds(
        (const __attribute__((address_space(1))) void*)g,
        (__attribute__((address_space(3))) void*)l, 16, 0, 0);
}

// ---------------- fused prep (one launch; branches are block-uniform) ----------------
// [0, NB_CVT)                 : x fp32 -> bf16 [MPAD][512], zero pad rows
// [+, NB_DEG)                 : degree atomics
// [+, NB_W12)                 : W1 [512][512] -> W1T [512][512] (transposed bf16)
// [+, NB_W12)                 : W2 likewise
// [+, NB_W3)                  : W3 [512][256] -> W3T [256][512]
// [+, NB_WP)                  : Wp [256][128] -> WpT [128][256]
// [+, NB_EMB)                 : eb[c][:] = bf16(emb[cidx[c]][:]), c in [0, N_C)
__global__ __launch_bounds__(256) void prep_fused(
    const float* __restrict__ x, u16* __restrict__ xb,
    const int* __restrict__ src, const int* __restrict__ dst,
    int* __restrict__ degO, int* __restrict__ degI,
    const float* __restrict__ W1, u16* __restrict__ W1T,
    const float* __restrict__ W2, u16* __restrict__ W2T,
    const float* __restrict__ W3, u16* __restrict__ W3T,
    const float* __restrict__ Wp, u16* __restrict__ WpT,
    const float* __restrict__ emb, const int* __restrict__ cidx,
    u16* __restrict__ eb) {
    int b = blockIdx.x;
    const int t = threadIdx.x;
    if (b < NB_CVT) {
        int base = (b * 256 + t) * 4;
        int m = base >> 9;
        ushort4 o;
        if (m < N_NODES) {
            float4 v = *(const float4*)(x + base);
            o.x = f2bf(v.x); o.y = f2bf(v.y); o.z = f2bf(v.z); o.w = f2bf(v.w);
        } else {
            o = make_ushort4(0, 0, 0, 0);
        }
        *(ushort4*)(xb + base) = o;
        return;
    }
    b -= NB_CVT;
    if (b < NB_DEG) {
        int e = b * 256 + t;
        if (e < N_EDGES) {
            atomicAdd(&degO[src[e]], 1);
            atomicAdd(&degI[dst[e]], 1);
        }
        return;
    }
    b -= NB_DEG;
    if (b < NB_W12) {  // W1: K=512, N=512
        int i = b * 256 + t;
        int n = i >> 9, k = i & 511;
        W1T[i] = f2bf(W1[(k << 9) + n]);
        return;
    }
    b -= NB_W12;
    if (b < NB_W12) {  // W2: K=512, N=512
        int i = b * 256 + t;
        int n = i >> 9, k = i & 511;
        W2T[i] = f2bf(W2[(k << 9) + n]);
        return;
    }
    b -= NB_W12;
    if (b < NB_W3) {   // W3: K=512, N=256
        int i = b * 256 + t;
        int n = i >> 9, k = i & 511;
        W3T[i] = f2bf(W3[(k << 8) + n]);
        return;
    }
    b -= NB_W3;
    if (b < NB_WP) {   // Wp: K=256, N=128
        int i = b * 256 + t;
        int n = i >> 8, k = i & 255;
        WpT[i] = f2bf(Wp[(k << 7) + n]);
        return;
    }
    b -= NB_WP;
    {                  // gather_emb: 2 cells per block, N_C=1024 cells total
        int idx = b * 256 + t;
        int c = idx >> 7, f = idx & 127;
        eb[idx] = f2bf(emb[(size_t)cidx[c] * N_DIM + f]);
    }
}

// --- 3-phase parallel exclusive scan of degI -> offs[0..N_NODES] ---
__global__ void scan_blocksum_kernel(const int* __restrict__ deg, int* __restrict__ bsum) {
    __shared__ int sh[SCAN_B];
    int i = blockIdx.x * SCAN_B + threadIdx.x;
    int v = (i < N_NODES) ? deg[i] : 0;
    sh[threadIdx.x] = v;
    __syncthreads();
    for (int off = SCAN_B / 2; off > 0; off >>= 1) {
        if (threadIdx.x < off) sh[threadIdx.x] += sh[threadIdx.x + off];
        __syncthreads();
    }
    if (threadIdx.x == 0) bsum[blockIdx.x] = sh[0];
}

__global__ void scan_bsum_kernel(const int* __restrict__ bsum, int* __restrict__ boff) {
    __shared__ int sh[SCAN_B];
    const int t = threadIdx.x;
    int v = (t < SCAN_NB) ? bsum[t] : 0;
    sh[t] = v;
    __syncthreads();
    for (int off = 1; off < SCAN_B; off <<= 1) {
        int u = (t >= off) ? sh[t - off] : 0;
        __syncthreads();
        sh[t] += u;
        __syncthreads();
    }
    if (t < SCAN_NB) boff[t] = sh[t] - v;  // exclusive
}

__global__ void scan_final_kernel(const int* __restrict__ deg, const int* __restrict__ boff,
                                  int* __restrict__ offs) {
    __shared__ int sh[SCAN_B];
    const int t = threadIdx.x;
    int i = blockIdx.x * SCAN_B + t;
    int v = (i < N_NODES) ? deg[i] : 0;
    sh[t] = v;
    __syncthreads();
    for (int off = 1; off < SCAN_B; off <<= 1) {
        int u = (t >= off) ? sh[t - off] : 0;
        __syncthreads();
        sh[t] += u;
        __syncthreads();
    }
    if (i < N_NODES) offs[i] = boff[blockIdx.x] + sh[t] - v;
    if (i == 0) offs[N_NODES] = N_EDGES;  // total degree = edge count
}

// ---------------- fused fill_csr + norms (both depend only on degrees/scan) -------------
__global__ __launch_bounds__(256) void csr_norms_fused(
    const int* __restrict__ src, const int* __restrict__ dst,
    int* __restrict__ cursor, const int* __restrict__ offs,
    int* __restrict__ csr,
    const int* __restrict__ degO, const int* __restrict__ degI,
    float* __restrict__ ns, float* __restrict__ nd) {
    int b = blockIdx.x;
    const int t = threadIdx.x;
    if (b < NB_DEG) {
        int e = b * 256 + t;
        if (e < N_EDGES) {
            int d = dst[e];
            int slot = atomicAdd(&cursor[d], 1);
            csr[offs[d] + slot] = src[e];
        }
        return;
    }
    b -= NB_DEG;
    int i = b * 256 + t;
    if (i < N_NODES) {
        ns[i] = degO[i] > 0 ? rsqrtf((float)degO[i]) : 0.f;
        nd[i] = degI[i] > 0 ? rsqrtf((float)degI[i]) : 0.f;
    }
}

// ---------------- MFMA GEMM (NT: A[M][K] bf16, B[N][K] bf16) ----------------
// C = A @ B^T ; optional A-row gather (aidx), row scale, col bias, relu;
// bf16 or f32 out.  128x128 tile, 256 threads / 4 waves, wave tile 64x64.
// v0 schedule (PROVEN BEST across v0/v2/v4/v7/v8): 2 LDS buffers, one
// __syncthreads per K-iter, DMA for iter k+1 issued right after barrier k.
// Chunk-XOR swizzle (verified correct; conflict-free, perf-neutral).
__global__ __launch_bounds__(256, 4) void gemm_bf16_nt(
    const u16* __restrict__ A, const u16* __restrict__ B,
    const int* __restrict__ aidx,
    u16* __restrict__ Cb, float* __restrict__ Cf,
    const float* __restrict__ scale, int nScale,
    const float* __restrict__ bias, int doRelu,
    int N, int K) {
    __shared__ __align__(16) u16 As[2 * 4096];  // 2 buffers x 128x32
    __shared__ __align__(16) u16 Bs[2 * 4096];
    const int t = threadIdx.x;
    const int m0 = blockIdx.x * 128, n0 = blockIdx.y * 128;
    const int l = t & 63, w = t >> 6;
    const int wm = (w >> 1) << 6, wn = (w & 1) << 6;
    const int lr = l & 15, quad = l >> 4;

    const int lrow = l >> 2;
    const int kof = (((l & 3) ^ ((l >> 3) & 3)) << 3);
    const int r0 = w, r1 = w + 4;
    int ar0 = m0 + r0 * 16 + lrow;
    int ar1 = m0 + r1 * 16 + lrow;
    if (aidx) { ar0 = aidx[ar0]; ar1 = aidx[ar1]; }
    const u16* gA0 = A + (size_t)ar0 * K + kof;
    const u16* gA1 = A + (size_t)ar1 * K + kof;
    const u16* gB0 = B + (size_t)(n0 + r0 * 16 + lrow) * K + kof;
    const u16* gB1 = B + (size_t)(n0 + r1 * 16 + lrow) * K + kof;
    u16* lA0 = As + r0 * 512;  // wave-uniform LDS bases (buf0; buf1 = +4096)
    u16* lA1 = As + r1 * 512;
    u16* lB0 = Bs + r0 * 512;
    u16* lB1 = Bs + r1 * 512;

    f32x4 acc[4][4] = {};

    // prologue: stage iter 0 into buf0
    async_copy16(gA0, lA0);
    async_copy16(gA1, lA1);
    async_copy16(gB0, lB0);
    async_copy16(gB1, lB1);

    const int qoff = ((quad ^ ((l >> 1) & 3)) << 3);

    const int niter = K >> 5;
    for (int it = 0; it < niter; ++it) {
        const int cur = (it & 1) << 12;   // 0 / 4096
        const int nxt = 4096 - cur;
        __syncthreads();  // drains DMA into buf[cur]; prior reads of buf[nxt] done
        if (it + 1 < niter) {
            const int ks = (it + 1) << 5;
            async_copy16(gA0 + ks, lA0 + nxt);
            async_copy16(gA1 + ks, lA1 + nxt);
            async_copy16(gB0 + ks, lB0 + nxt);
            async_copy16(gB1 + ks, lB1 + nxt);
        }
        bf16x8 af[4], bg[4];
#pragma unroll
        for (int i = 0; i < 4; ++i)
            af[i] = *(const bf16x8*)&As[cur + (wm + i * 16 + lr) * 32 + qoff];
#pragma unroll
        for (int j = 0; j < 4; ++j)
            bg[j] = *(const bf16x8*)&Bs[cur + (wn + j * 16 + lr) * 32 + qoff];
#pragma unroll
        for (int i = 0; i < 4; ++i)
#pragma unroll
            for (int j = 0; j < 4; ++j)
                acc[i][j] = __builtin_amdgcn_mfma_f32_16x16x32_bf16(af[i], bg[j], acc[i][j], 0, 0, 0);
    }

    // C/D layout (m89-verified): col = lane&15, row = quad*4 + reg
#pragma unroll
    for (int i = 0; i < 4; ++i) {
        int rbase = m0 + wm + i * 16 + quad * 4;
#pragma unroll
        for (int j = 0; j < 4; ++j) {
            int col = n0 + wn + j * 16 + lr;
            float bv = bias ? bias[col] : 0.f;
#pragma unroll
            for (int r = 0; r < 4; ++r) {
                int rg = rbase + r;
                float sc = scale ? (rg < nScale ? scale[rg] : 0.f) : 1.f;
                float v = acc[i][j][r] * sc + bv;
                if (doRelu) v = fmaxf(v, 0.f);
                if (Cb) Cb[(size_t)rg * N + col] = f2bf(v);
                else    Cf[(size_t)rg * N + col] = v;
            }
        }
    }
}

// ---------------- CSR aggregation: H[n] = nsOut[n]? * relu(nd[n]*sum T[s] + b) -------------
template <int W32>  // u32 words per lane: 4 (F=512) or 2 (F=256)
struct AggVec;
template <> struct AggVec<4> { using T = uint4; };
template <> struct AggVec<2> { using T = uint2; };

template <int F>
__global__ __launch_bounds__(256) void aggregate_kernel(
    const u16* __restrict__ T, const int* __restrict__ csr,
    const int* __restrict__ offs, const float* __restrict__ nd,
    const float* __restrict__ bias, const float* __restrict__ nsOut,
    u16* __restrict__ H) {
    constexpr int W32 = F / 128;  // u32 words per lane
    using VT = typename AggVec<W32>::T;
    const int t = threadIdx.x, w = t >> 6, l = t & 63;
    const int node = blockIdx.x * 4 + w;
    u32* __restrict__ Hrow = (u32*)H + (size_t)node * (F / 2) + l * W32;
    if (node >= N_NODES) {
        VT z = {};
        *(VT*)Hrow = z;
        return;
    }
    const int s0 = __builtin_amdgcn_readfirstlane(offs[node]);
    const int s1 = __builtin_amdgcn_readfirstlane(offs[node + 1]);
    const u32* __restrict__ Tb = (const u32*)T + l * W32;

    float acc[4][2 * W32];
#pragma unroll
    for (int c = 0; c < 4; ++c)
#pragma unroll
        for (int j = 0; j < 2 * W32; ++j) acc[c][j] = 0.f;

    int e = s0;
    for (; e + 8 <= s1; e += 8) {  // 8 loads in flight, 4 accumulator chains
        int si[8];
#pragma unroll
        for (int c = 0; c < 8; ++c) si[c] = csr[e + c];
        VT v[8];
#pragma unroll
        for (int c = 0; c < 8; ++c)
            v[c] = *(const VT*)(Tb + (size_t)si[c] * (F / 2));
#pragma unroll
        for (int c = 0; c < 8; ++c) {
            const u32* vv = (const u32*)&v[c];
#pragma unroll
            for (int j = 0; j < W32; ++j) {
                acc[c & 3][2 * j] += bf2f(vv[j] & 0xffffu);
                acc[c & 3][2 * j + 1] += bf2f(vv[j] >> 16);
            }
        }
    }
    for (; e + 4 <= s1; e += 4) {
        int si[4];
#pragma unroll
        for (int c = 0; c < 4; ++c) si[c] = csr[e + c];
        VT v[4];
#pragma unroll
        for (int c = 0; c < 4; ++c)
            v[c] = *(const VT*)(Tb + (size_t)si[c] * (F / 2));
#pragma unroll
        for (int c = 0; c < 4; ++c) {
            const u32* vv = (const u32*)&v[c];
#pragma unroll
            for (int j = 0; j < W32; ++j) {
                acc[c][2 * j] += bf2f(vv[j] & 0xffffu);
                acc[c][2 * j + 1] += bf2f(vv[j] >> 16);
            }
        }
    }
    for (; e < s1; ++e) {
        int s = csr[e];
        VT v = *(const VT*)(Tb + (size_t)s * (F / 2));
        const u32* vv = (const u32*)&v;
#pragma unroll
        for (int j = 0; j < W32; ++j) {
            acc[0][2 * j] += bf2f(vv[j] & 0xffffu);
            acc[0][2 * j + 1] += bf2f(vv[j] >> 16);
        }
    }

    const float ndv = nd[node];
    const float nsv = nsOut ? nsOut[node] : 1.f;
    u32 ow[W32];
#pragma unroll
    for (int j = 0; j < W32; ++j) {
        float a0 = acc[0][2 * j] + acc[1][2 * j] + acc[2][2 * j] + acc[3][2 * j];
        float a1 = acc[0][2 * j + 1] + acc[1][2 * j + 1] + acc[2][2 * j + 1] + acc[3][2 * j + 1];
        float r0 = fmaxf(fmaf(a0, ndv, bias[l * 2 * W32 + 2 * j]), 0.f) * nsv;
        float r1 = fmaxf(fmaf(a1, ndv, bias[l * 2 * W32 + 2 * j + 1]), 0.f) * nsv;
        ow[j] = (u32)f2bf(r0) | ((u32)f2bf(r1) << 16);
    }
    VT o;
    u32* op = (u32*)&o;
#pragma unroll
    for (int j = 0; j < W32; ++j) op[j] = ow[j];
    *(VT*)Hrow = o;
}

// ---------------- selected-destination aggregation (layer 3, F=512) ----------------
// S[slot] = nd[xidx[slot]] * sum_{src in N(xidx[slot])} Tn[src]
__global__ __launch_bounds__(256) void aggregate_sel_kernel(
    const u16* __restrict__ Tn, const int* __restrict__ csr,
    const int* __restrict__ offs, const float* __restrict__ nd,
    const int* __restrict__ xidx, u16* __restrict__ S) {
    const int t = threadIdx.x, w = t >> 6, l = t & 63;
    const int slot = blockIdx.x * 4 + w;
    const int node = __builtin_amdgcn_readfirstlane(xidx[slot]);
    const int s0 = __builtin_amdgcn_readfirstlane(offs[node]);
    const int s1 = __builtin_amdgcn_readfirstlane(offs[node + 1]);
    const u32* __restrict__ Tb = (const u32*)Tn + l * 4;
    u32* __restrict__ Srow = (u32*)S + (size_t)slot * 256 + l * 4;

    float acc[4][8];
#pragma unroll
    for (int c = 0; c < 4; ++c)
#pragma unroll
        for (int j = 0; j < 8; ++j) acc[c][j] = 0.f;

    int e = s0;
    for (; e + 8 <= s1; e += 8) {
        int si[8];
#pragma unroll
        for (int c = 0; c < 8; ++c) si[c] = csr[e + c];
        uint4 v[8];
#pragma unroll
        for (int c = 0; c < 8; ++c)
            v[c] = *(const uint4*)(Tb + (size_t)si[c] * 256);
#pragma unroll
        for (int c = 0; c < 8; ++c) {
            const u32* vv = (const u32*)&v[c];
#pragma unroll
            for (int j = 0; j < 4; ++j) {
                acc[c & 3][2 * j] += bf2f(vv[j] & 0xffffu);
                acc[c & 3][2 * j + 1] += bf2f(vv[j] >> 16);
            }
        }
    }
    for (; e + 4 <= s1; e += 4) {
        int si[4];
#pragma unroll
        for (int c = 0; c < 4; ++c) si[c] = csr[e + c];
        uint4 v[4];
#pragma unroll
        for (int c = 0; c < 4; ++c)
            v[c] = *(const uint4*)(Tb + (size_t)si[c] * 256);
#pragma unroll
        for (int c = 0; c < 4; ++c) {
            const u32* vv = (const u32*)&v[c];
#pragma unroll
            for (int j = 0; j < 4; ++j) {
                acc[c][2 * j] += bf2f(vv[j] & 0xffffu);
                acc[c][2 * j + 1] += bf2f(vv[j] >> 16);
            }
        }
    }
    for (; e < s1; ++e) {
        int s = csr[e];
        uint4 v = *(const uint4*)(Tb + (size_t)s * 256);
        const u32* vv = (const u32*)&v;
#pragma unroll
        for (int j = 0; j < 4; ++j) {
            acc[0][2 * j] += bf2f(vv[j] & 0xffffu);
            acc[0][2 * j + 1] += bf2f(vv[j] >> 16);
        }
    }

    const float ndv = nd[node];
    uint4 o;
    u32* op = (u32*)&o;
#pragma unroll
    for (int j = 0; j < 4; ++j) {
        float a0 = (acc[0][2 * j] + acc[1][2 * j] + acc[2][2 * j] + acc[3][2 * j]) * ndv;
        float a1 = (acc[0][2 * j + 1] + acc[1][2 * j + 1] + acc[2][2 * j + 1] + acc[3][2 * j + 1]) * ndv;
        op[j] = (u32)f2bf(a0) | ((u32)f2bf(a1) << 16);
    }
    *(uint4*)Srow = o;
}

// ---------------- launch ----------------

extern "C" void kernel_launch(void* const* d_in, const int* in_sizes, int n_in,
                              void* d_out, int out_size, void* d_ws, size_t ws_size,
                              hipStream_t stream) {
    const float* x   = (const float*)d_in[0];
    const int*   src = (const int*)d_in[1];
    const int*   dst = (const int*)d_in[2];
    const int*   xidx= (const int*)d_in[3];
    const int*   cidx= (const int*)d_in[4];
    const float* W1  = (const float*)d_in[5];
    const float* b1  = (const float*)d_in[6];
    const float* W2  = (const float*)d_in[7];
    const float* b2  = (const float*)d_in[8];
    const float* W3  = (const float*)d_in[9];
    const float* b3  = (const float*)d_in[10];
    const float* Wp  = (const float*)d_in[11];
    const float* bp  = (const float*)d_in[12];
    const float* emb = (const float*)d_in[13];
    float* out = (float*)d_out;

    char* p = (char*)d_ws;
    auto alloc = [&](size_t bytes) {
        char* r = p;
        p += (bytes + 255) & ~(size_t)255;
        return r;
    };
    u16* T    = (u16*)alloc((size_t)MPAD * 512 * 2);   // transformed features (bf16, ns-scaled)
    u16* HX   = (u16*)alloc((size_t)MPAD * 512 * 2);   // x_bf16 / h1 / h2' (in-place rotate)
    u16* W1T  = (u16*)alloc((size_t)512 * 512 * 2);
    u16* W2T  = (u16*)alloc((size_t)512 * 512 * 2);
    u16* W3T  = (u16*)alloc((size_t)256 * 512 * 2);
    u16* WpT  = (u16*)alloc((size_t)128 * 256 * 2);
    u16* Ssel = (u16*)alloc((size_t)N_SEL * 512 * 2);  // selected aggregate (layer 3 input)
    u16* encb = (u16*)alloc((size_t)N_SEL * OUT_F * 2);
    u16* projb= (u16*)alloc((size_t)N_SEL * N_DIM * 2);
    u16* eb   = (u16*)alloc((size_t)N_C * N_DIM * 2);
    int* degO   = (int*)alloc(N_NODES * 4);
    int* degI   = (int*)alloc(N_NODES * 4);
    int* cursor = (int*)alloc(N_NODES * 4);
    int* offs   = (int*)alloc((N_NODES + 1) * 4);
    float* ns   = (float*)alloc(N_NODES * 4);
    float* nd   = (float*)alloc(N_NODES * 4);
    int* csr    = (int*)alloc(N_EDGES * 4);
    int* bsum   = (int*)alloc(SCAN_NB * 4);
    int* boff   = (int*)alloc(SCAN_NB * 4);
    if ((size_t)(p - (char*)d_ws) > ws_size) return;  // scratch too small — bail

    // zero degO, degI, cursor (contiguous)
    hipMemsetAsync(degO, 0, (size_t)((char*)offs - (char*)degO), stream);

    // fused prep: convert_x + degrees + 4 weight transposes + emb gather (1 launch)
    const int prep_grid = NB_CVT + NB_DEG + 2 * NB_W12 + NB_W3 + NB_WP + NB_EMB;
    prep_fused<<<prep_grid, 256, 0, stream>>>(
        x, HX, src, dst, degO, degI, W1, W1T, W2, W2T, W3, W3T, Wp, WpT, emb, cidx, eb);

    // scan of degI -> offs
    scan_blocksum_kernel<<<SCAN_NB, SCAN_B, 0, stream>>>(degI, bsum);
    scan_bsum_kernel<<<1, SCAN_B, 0, stream>>>(bsum, boff);
    scan_final_kernel<<<SCAN_NB, SCAN_B, 0, stream>>>(degI, boff, offs);

    // fused fill_csr + norms (1 launch)
    csr_norms_fused<<<NB_DEG + SCAN_NB, 256, 0, stream>>>(
        src, dst, cursor, offs, csr, degO, degI, ns, nd);

    // layer 1: T = (ns.x) @ W1 ; h1 = relu(nd * agg(T) + b1)
    gemm_bf16_nt<<<dim3(MPAD / 128, 512 / 128), 256, 0, stream>>>(
        HX, W1T, nullptr, T, nullptr, ns, N_NODES, nullptr, 0, 512, 512);
    aggregate_kernel<512><<<MPAD / 4, 256, 0, stream>>>(T, csr, offs, nd, b1, nullptr, HX);
    // layer 2: T = (ns.h1) @ W2 ; h2' = ns * relu(nd * agg(T) + b2)   (ns pre-applied for layer 3)
    gemm_bf16_nt<<<dim3(MPAD / 128, 512 / 128), 256, 0, stream>>>(
        HX, W2T, nullptr, T, nullptr, ns, N_NODES, nullptr, 0, 512, 512);
    aggregate_kernel<512><<<MPAD / 4, 256, 0, stream>>>(T, csr, offs, nd, b2, ns, HX);
    // layer 3 AGGREGATE-FIRST at the 8192 selected destinations only:
    // Ssel[s] = nd[xidx[s]] * sum h2'[src] ; enc = relu(Ssel @ W3 + b3)
    aggregate_sel_kernel<<<N_SEL / 4, 256, 0, stream>>>(HX, csr, offs, nd, xidx, Ssel);
    gemm_bf16_nt<<<dim3(N_SEL / 128, 256 / 128), 256, 0, stream>>>(
        Ssel, W3T, nullptr, encb, nullptr, nullptr, 0, b3, 1, 256, 512);

    // proj = enc @ Wp + bp   (enc already in x_indices order — no gather)
    gemm_bf16_nt<<<dim3(N_SEL / 128, 1), 256, 0, stream>>>(
        encb, WpT, nullptr, projb, nullptr, nullptr, 0, bp, 0, N_DIM, 256);
    // out = e @ proj^T   (fp32 output)
    gemm_bf16_nt<<<dim3(N_C / 128, N_SEL / 128), 256, 0, stream>>>(
        eb, projb, nullptr, nullptr, out, nullptr, 0, nullptr, 0, N_SEL, N_DIM);
}